// Round 5
// baseline (211.892 us; speedup 1.0000x reference)
//
#include <hip/hip_runtime.h>
#include <cstdint>

#define BB 8
#define CC 128
#define HH 96
#define WW 160
#define HWsz (HH * WW)          // 15360
#define TH 8
#define TW 32
#define CSTEP 8
#define HALO_H (TH + 8)         // 16
#define HALO_W (TW + 8)         // 40
#define CH_WORDS (HALO_H * HALO_W)       // 640
#define CHUNK_WORDS (CSTEP * CH_WORDS)   // 5120 words = 20 KB per buffer
#define NWAVES 9
#define NTHREADS (NWAVES * 64)           // 576
#define WLOADS (CHUNK_WORDS / 64)        // 80 wave-sized dword loads per chunk
#define NCHUNKS (CC / CSTEP)             // 16
#define NBLOCKS (BB * (HH / TH) * (WW / TW))  // 480

__device__ __forceinline__ void g2l_dword(const float* g, float* l) {
  __builtin_amdgcn_global_load_lds((const __attribute__((address_space(1))) void*)g,
                                   (__attribute__((address_space(3))) void*)l,
                                   4, 0, 0);
}

// launch_bounds(576,2): VGPR cap ~113. R2/R3: allocator pressure spills
// acc[9][4] -> ~800MB scratch HBM traffic. Sentinel: WRITE_SIZE must stay
// exactly 38880 KB.
extern "C" __global__ void __launch_bounds__(NTHREADS, 2)
corr81_kernel(const float* __restrict__ x1, const float* __restrict__ x2,
              float* __restrict__ out)
{
  __shared__ __align__(16) float lds[2][CHUNK_WORDS];  // ping-pong, 40 KB

  const int tid  = threadIdx.x;
  const int wv   = tid >> 6;     // dy index 0..8 (wave-uniform)
  const int lane = tid & 63;
  const int r    = lane >> 3;    // tile row 0..7
  const int j    = lane & 7;     // w-slot 0..7 (4 px each)

  const int bid = blockIdx.x;
  const int wt  = bid % (WW / TW);
  const int ht  = (bid / (WW / TW)) % (HH / TH);
  const int b   = bid / ((WW / TW) * (HH / TH));
  const int h0  = ht * TH;
  const int w0  = wt * TW;

  // Per-lane x2 staging offsets (word offsets, chunk-invariant; replicate-pad
  // clamping folded in). Verified round-1 scheme.
  uint32_t soff[9];
#pragma unroll
  for (int i = 0; i < 9; ++i) {
    const int idx = wv + 9 * i;          // wave-load slot 0..80
    const int e   = idx * 64 + lane;     // LDS word this lane fills
    const int ci  = e / CH_WORDS;        // channel within chunk
    const int rem = e - ci * CH_WORDS;
    const int hr  = rem / HALO_W;        // halo row 0..15
    const int wh  = rem - hr * HALO_W;   // halo col 0..39
    int gh = h0 + hr - 4; gh = gh < 0 ? 0 : (gh > HH - 1 ? HH - 1 : gh);
    int gw = w0 + wh - 4; gw = gw < 0 ? 0 : (gw > WW - 1 ? WW - 1 : gw);
    soff[i] = (uint32_t)((ci * HH + gh) * WW + gw);
  }

  const float* x2b = x2 + (size_t)b * CC * HWsz;
  const float* x1b = x1 + (size_t)b * CC * HWsz + (size_t)(h0 + r) * WW + (w0 + 4 * j);

  float acc[9][4];
#pragma unroll
  for (int dx = 0; dx < 9; ++dx)
#pragma unroll
    for (int p = 0; p < 4; ++p) acc[dx][p] = 0.f;

  const int rowbase = (r + wv) * HALO_W + 4 * j;

  // ---- prologue: stage chunk 0 into buffer 0
  {
    const float* src = x2b;
#pragma unroll
    for (int i = 0; i < 9; ++i) {
      const int idx = wv + 9 * i;
      if (idx < WLOADS)                       // wave-uniform
        g2l_dword(src + soff[i], &lds[0][idx * 64]);
    }
  }
  __syncthreads();

  // ---- pipeline with vmcnt-order fix: per wave the VMEM queue must be
  // [8 x1 loads][~9 staging loads]. vmcnt retires IN ORDER, so consuming x1
  // costs vmcnt(9) (oldest-first) while staging drains only at the barrier,
  // fully covered by compute. (R4 had staging first -> consuming x1 drained
  // the whole next-chunk staging -> no overlap, R4==R1.)
#pragma unroll 1
  for (int chunk = 0; chunk < NCHUNKS; ++chunk) {
    const int cb = chunk & 1;        // compute buffer
    const int sb = cb ^ 1;           // stage buffer

    // (1) x1 loads for THIS chunk — issued first, oldest in vmcnt queue
    float4 a[CSTEP];
#pragma unroll
    for (int ci = 0; ci < CSTEP; ++ci)
      a[ci] = *(const float4*)(x1b + (size_t)(chunk * CSTEP + ci) * HWsz);

    __builtin_amdgcn_sched_barrier(0);   // pin: staging must not hoist above x1

    // (2) stage NEXT chunk
    if (chunk + 1 < NCHUNKS) {
      const float* src = x2b + (size_t)(chunk + 1) * (CSTEP * HWsz);
#pragma unroll
      for (int i = 0; i < 9; ++i) {
        const int idx = wv + 9 * i;
        if (idx < WLOADS)
          g2l_dword(src + soff[i], &lds[sb][idx * 64]);
      }
    }

    __builtin_amdgcn_sched_barrier(0);   // pin: compute stays below staging issue

    // (3) compute THIS chunk: LDS (lgkmcnt) + pre-loaded x1 registers
#pragma unroll
    for (int ci = 0; ci < CSTEP; ++ci) {
      const float av[4] = {a[ci].x, a[ci].y, a[ci].z, a[ci].w};
      const float4* wr = (const float4*)&lds[cb][ci * CH_WORDS + rowbase];
      const float4 f0 = wr[0];
      const float4 f1 = wr[1];
      const float4 f2 = wr[2];
      const float w12[12] = {f0.x, f0.y, f0.z, f0.w,
                             f1.x, f1.y, f1.z, f1.w,
                             f2.x, f2.y, f2.z, f2.w};
#pragma unroll
      for (int dx = 0; dx < 9; ++dx)
#pragma unroll
        for (int p = 0; p < 4; ++p)
          acc[dx][p] = fmaf(av[p], w12[dx + p], acc[dx][p]);
    }

    __syncthreads();   // staging issued ~5K cyc ago; vmcnt(0) drain is cheap
  }

  // epilogue: out[((b*81 + wv*9+dx)*H + h0+r)*W + w0+4j ...], scale 1/8
  float* op = out + (((size_t)b * 81 + (size_t)wv * 9) * HH + (h0 + r)) * WW + (w0 + 4 * j);
#pragma unroll
  for (int dx = 0; dx < 9; ++dx) {
    float4 v;
    v.x = acc[dx][0] * 0.125f;
    v.y = acc[dx][1] * 0.125f;
    v.z = acc[dx][2] * 0.125f;
    v.w = acc[dx][3] * 0.125f;
    *(float4*)(op + (size_t)dx * HWsz) = v;
  }
}

extern "C" void kernel_launch(void* const* d_in, const int* in_sizes, int n_in,
                              void* d_out, int out_size, void* d_ws, size_t ws_size,
                              hipStream_t stream) {
  const float* x1 = (const float*)d_in[0];
  const float* x2 = (const float*)d_in[1];
  float* out = (float*)d_out;
  corr81_kernel<<<dim3(NBLOCKS), dim3(NTHREADS), 0, stream>>>(x1, x2, out);
}